// Round 13
// baseline (696.523 us; speedup 1.0000x reference)
//
#include <hip/hip_runtime.h>
#include <math.h>

// Problem constants
#define T_TOK 8192   // B*S tokens
#define DIM   1024   // D
#define HID   2816   // H
#define NE    8      // experts
// K (top-k) = 2

typedef __attribute__((ext_vector_type(4))) float  f32x4;
typedef __attribute__((ext_vector_type(8))) __bf16 bf16x8;
typedef __attribute__((ext_vector_type(8))) unsigned short u16x8;

__device__ __forceinline__ unsigned short f2bf(float f) {
  unsigned int u = __builtin_bit_cast(unsigned int, f);
  unsigned int r = (u + 0x7FFFu + ((u >> 16) & 1u)) >> 16;   // RTNE
  return (unsigned short)r;
}
__device__ __forceinline__ int imin(int a, int b) { return a < b ? a : b; }

// global -> LDS direct DMA, 16B per lane. LDS dest = wave-uniform base + lane*16.
typedef const __attribute__((address_space(1))) void gvoid_t;
typedef __attribute__((address_space(3))) void svoid_t;
__device__ __forceinline__ void g2l16(const void* g, void* l) {
  __builtin_amdgcn_global_load_lds((gvoid_t*)g, (svoid_t*)l, 16, 0, 0);
}

// Pipeline fences (T3/T4): raw s_barrier + counted waits; sched_barrier pins motion.
#define WAITV(N) asm volatile("s_waitcnt vmcnt(" #N ")" ::: "memory")
#define WAITV0 asm volatile("s_waitcnt vmcnt(0)" ::: "memory")
#define LGKM0  asm volatile("s_waitcnt lgkmcnt(0)" ::: "memory")
#define FENCE  asm volatile("" ::: "memory")
#define SBAR   __builtin_amdgcn_s_barrier()
#define SCHED0 __builtin_amdgcn_sched_barrier(0)
#define PRIO(x) __builtin_amdgcn_s_setprio(x)
#define PH_PRE  do { FENCE; SBAR; LGKM0; SCHED0; PRIO(1); } while (0)
#define PH_POST do { PRIO(0); FENCE; SBAR; SCHED0; } while (0)

#define NT1 (HID / 128)   // 22 (gemm1 BN=128)
#define NT2 (DIM / 256)   // 4  (gemm2 BN=256)
#define TPM ((DIM / 64) * (HID / 64) * NE)   // 5632 64x64 tiles per matrix
#define RTB (T_TOK / 4)   // 2048 router blocks
#define TBLK ((3 * TPM) / 2)                 // 8448 transpose blocks (2 tiles each)
#define LDSTR 65          // LDS tile row stride in floats: 2-way banks both phases

// ===== fused front: router (bid < RTB) + 3x transpose-cast (2 tiles/blk, pipelined) =====
__global__ __launch_bounds__(256) void front_kernel(const float* __restrict__ x,
                                                    const float* __restrict__ gw,
                                                    const float* __restrict__ w1,
                                                    const float* __restrict__ w3,
                                                    const float* __restrict__ w2,
                                                    unsigned short* __restrict__ xb,
                                                    unsigned short* __restrict__ w1t,
                                                    unsigned short* __restrict__ w3t,
                                                    unsigned short* __restrict__ w2t,
                                                    int* __restrict__ cnt,
                                                    int* __restrict__ idx,
                                                    float* __restrict__ wslot) {
  __shared__ float lds[64 * LDSTR];   // 16.6 KB (router blocks don't touch)
  int bid = blockIdx.x;
  if (bid < RTB) {
    // ---------------- router (fused x->bf16 cast) ----------------
    int wid = threadIdx.x >> 6;
    int lane = threadIdx.x & 63;
    int t = bid * 4 + wid;
    double acc[NE];
#pragma unroll
    for (int e = 0; e < NE; ++e) acc[e] = 0.0;
    const float* xr = x + (size_t)t * DIM;
    unsigned short* xbr = xb + (size_t)t * DIM;
#pragma unroll 4
    for (int i = 0; i < DIM / 64; ++i) {
      int d = i * 64 + lane;
      float xf = xr[d];
      xbr[d] = f2bf(xf);
      double xv = (double)xf;
#pragma unroll
      for (int e = 0; e < NE; ++e) acc[e] += xv * (double)gw[e * DIM + d];
    }
#pragma unroll
    for (int e = 0; e < NE; ++e) {
#pragma unroll
      for (int off = 32; off >= 1; off >>= 1) acc[e] += __shfl_xor(acc[e], off);
    }
    if (lane == 0) {
      int e0 = 0; double s0 = acc[0];
#pragma unroll
      for (int e = 1; e < NE; ++e) if (acc[e] > s0) { s0 = acc[e]; e0 = e; }
      int e1 = -1; double s1 = -1.0e300;
#pragma unroll
      for (int e = 0; e < NE; ++e) if (e != e0 && acc[e] > s1) { s1 = acc[e]; e1 = e; }
      double w0 = 1.0 / (1.0 + exp(s1 - s0));   // softmax over {s0,s1}
      wslot[t] = (float)w0;
      wslot[T_TOK + t] = (float)(1.0 - w0);
      int p0 = atomicAdd(&cnt[e0], 1);
      idx[e0 * T_TOK + p0] = t;                 // slot 0
      int p1 = atomicAdd(&cnt[e1], 1);
      idx[e1 * T_TOK + p1] = t | (1 << 15);     // slot 1
    }
    return;
  }

  // -------- transpose-cast: fp32 [E][R][C] -> bf16 [E][C][R], 2 tiles pipelined --------
  int tb = bid - RTB;
  const int tr = threadIdx.x >> 4;            // 0..15
  const int tc4 = (threadIdx.x & 15) * 4;     // 0..60
  const int cw = threadIdx.x >> 3;            // 0..31
  const int r8 = (threadIdx.x & 7) * 8;       // 0..56

  const float* sA; unsigned short* dA; int cA, rA, RA;
  const float* sB; unsigned short* dB; int cB, rB, RB;
#pragma unroll
  for (int tau = 0; tau < 2; ++tau) {
    int g = tb * 2 + tau;
    int seg = g / TPM, rr = g % TPM;
    const float* srcm; unsigned short* dstm; int R, C;
    if (seg == 0)      { srcm = w1; dstm = w1t; R = DIM; C = HID; }
    else if (seg == 1) { srcm = w3; dstm = w3t; R = DIM; C = HID; }
    else               { srcm = w2; dstm = w2t; R = HID; C = DIM; }
    int per_e = (R / 64) * (C / 64);
    int e = rr / per_e, tt = rr % per_e;
    int nx = C / 64;
    int c0 = (tt % nx) * 64, r0 = (tt / nx) * 64;
    const float* s = srcm + (size_t)e * R * C + (size_t)(r0 + tr) * C + c0 + tc4;
    unsigned short* d = dstm + (size_t)e * R * C + (size_t)c0 * R + r0;
    if (tau == 0) { sA = s; dA = d; cA = C; rA = r0; RA = R; }
    else          { sB = s; dB = d; cB = C; rB = r0; RB = R; }
  }
  (void)rA; (void)rB;

  float4 v0[4], v1[4];
#pragma unroll
  for (int s4 = 0; s4 < 4; ++s4)
    v0[s4] = *(const float4*)(sA + (size_t)(s4 * 16) * cA);
  // LDS write tile0: row-major, stride 65 -> exact 2-way (free)
#pragma unroll
  for (int s4 = 0; s4 < 4; ++s4) {
    float* lr = &lds[(tr + s4 * 16) * LDSTR + tc4];
    lr[0] = v0[s4].x; lr[1] = v0[s4].y; lr[2] = v0[s4].z; lr[3] = v0[s4].w;
  }
  __syncthreads();
  // issue tile1 loads now; gather below hides their latency
#pragma unroll
  for (int s4 = 0; s4 < 4; ++s4)
    v1[s4] = *(const float4*)(sB + (size_t)(s4 * 16) * cB);
  // gather + store tile0: column reads at stride 65 -> 2-way
#pragma unroll
  for (int pass = 0; pass < 2; ++pass) {
    int c = cw + pass * 32;
    u16x8 o;
#pragma unroll
    for (int k = 0; k < 8; ++k) o[k] = f2bf(lds[(r8 + k) * LDSTR + c]);
    *(u16x8*)(dA + (size_t)c * RA + r8) = o;
  }
  __syncthreads();
#pragma unroll
  for (int s4 = 0; s4 < 4; ++s4) {
    float* lr = &lds[(tr + s4 * 16) * LDSTR + tc4];
    lr[0] = v1[s4].x; lr[1] = v1[s4].y; lr[2] = v1[s4].z; lr[3] = v1[s4].w;
  }
  __syncthreads();
#pragma unroll
  for (int pass = 0; pass < 2; ++pass) {
    int c = cw + pass * 32;
    u16x8 o;
#pragma unroll
    for (int k = 0; k < 8; ++k) o[k] = f2bf(lds[(r8 + k) * LDSTR + c]);
    *(u16x8*)(dB + (size_t)c * RB + r8) = o;
  }
}

// ===== self-decode: bid -> (e, n0, m0, c, base) straight from cnt[] =====
__device__ __forceinline__ bool decode_tile(const int* __restrict__ cnt, int ntiles_n,
                                            int nscale, int& e, int& n0, int& m0,
                                            int& c, int& base) {
  int nt = 0;
#pragma unroll
  for (int i = 0; i < NE; ++i) nt += ((cnt[i] + 255) >> 8) * ntiles_n;
  int q = nt >> 3, rr = nt & 7;
  int xcd = blockIdx.x & 7, pos = blockIdx.x >> 3;
  int cap = xcd < rr ? q + 1 : q;
  if (pos >= cap) return false;
  int lid = (xcd < rr ? xcd * (q + 1) : rr * (q + 1) + (xcd - rr) * q) + pos;
  int t1 = 0, s = 0;
  e = 0; c = 0; base = 0; n0 = 0; m0 = 0;
#pragma unroll
  for (int i = 0; i < NE; ++i) {
    int ci = cnt[i];
    int mi = (ci + 255) >> 8;
    int w = mi * ntiles_n;
    if (lid >= t1 && lid < t1 + w) {
      e = i; c = ci; base = s;
      int rem = lid - t1;
      int n = rem / mi;
      n0 = n * nscale;
      m0 = (rem - n * mi) * 256;
    }
    t1 += w; s += ci;
  }
  return true;
}

// ====== GEMM1: h = silu(Xg @ w1) * (Xg @ w3) — 2 phases/K-tile, counted vmcnt ======
// BM=256, BN=128 (dual-B), BK=64, 8 waves (2M x 4N), dbuf LDS 128KB.
__global__ __launch_bounds__(512, 1) void gemm1_kernel(const unsigned short* __restrict__ xb,
                                                       const unsigned short* __restrict__ w1t,
                                                       const unsigned short* __restrict__ w3t,
                                                       const int* __restrict__ cnt,
                                                       const int* __restrict__ idx,
                                                       unsigned short* __restrict__ hbuf) {
  int e, n0, m0, c, base;
  if (!decode_tile(cnt, NT1, 128, e, n0, m0, c, base)) return;

  __shared__ __align__(16) unsigned short As[2 * 16384];   // [2][256][64]
  __shared__ __align__(16) unsigned short B1s[2 * 8192];   // [2][128][64]
  __shared__ __align__(16) unsigned short B3s[2 * 8192];

  const int t = threadIdx.x;
  const int wid = t >> 6, lane = t & 63;
  const int wm = wid >> 2, wn = wid & 3;
  const int lr = lane & 15, kc = lane >> 4, sw = lane & 7;
  const int ldst = wid * 512;           // wave-uniform elems within an 8KB instr chunk
  const int trow = t >> 3;              // 0..63
  const int swzk = ((t & 7) ^ ((t >> 3) & 7)) * 8;   // pre-swizzled source k-chunk

  const int* idx_e = idx + e * T_TOK;
  int g0 = m0 + trow, g1 = m0 + 64 + trow, g2 = m0 + 128 + trow, g3 = m0 + 192 + trow;
  int tk0 = (g0 < c) ? (idx_e[g0] & 0x1FFF) : 0;
  int tk1 = (g1 < c) ? (idx_e[g1] & 0x1FFF) : 0;
  int tk2 = (g2 < c) ? (idx_e[g2] & 0x1FFF) : 0;
  int tk3 = (g3 < c) ? (idx_e[g3] & 0x1FFF) : 0;
  const unsigned short* aS0 = xb + (size_t)tk0 * DIM + swzk;
  const unsigned short* aS1 = xb + (size_t)tk1 * DIM + swzk;
  const unsigned short* aS2 = xb + (size_t)tk2 * DIM + swzk;
  const unsigned short* aS3 = xb + (size_t)tk3 * DIM + swzk;
  const unsigned short* w1e = w1t + ((size_t)e * HID + n0) * DIM;
  const unsigned short* w3e = w3t + ((size_t)e * HID + n0) * DIM;
  const unsigned short* b1S0 = w1e + (size_t)trow * DIM + swzk;
  const unsigned short* b1S1 = w1e + (size_t)(64 + trow) * DIM + swzk;
  const unsigned short* b3S0 = w3e + (size_t)trow * DIM + swzk;
  const unsigned short* b3S1 = w3e + (size_t)(64 + trow) * DIM + swzk;

  f32x4 acc1[8][2], acc3[8][2];
#pragma unroll
  for (int i = 0; i < 8; ++i)
#pragma unroll
    for (int j = 0; j < 2; ++j) {
      acc1[i][j] = f32x4{0.f, 0.f, 0.f, 0.f};
      acc3[i][j] = f32x4{0.f, 0.f, 0.f, 0.f};
    }
  bf16x8 ra0[4], ra1[4], rb1[2], rb3[2];

#define G1_STG_A(CUR, TILE) do {                                      \
    g2l16(aS0 + (TILE) * 64, As + (CUR) * 16384 + 0 * 4096 + ldst);   \
    g2l16(aS1 + (TILE) * 64, As + (CUR) * 16384 + 1 * 4096 + ldst);   \
    g2l16(aS2 + (TILE) * 64, As + (CUR) * 16384 + 2 * 4096 + ldst);   \
    g2l16(aS3 + (TILE) * 64, As + (CUR) * 16384 + 3 * 4096 + ldst);   \
  } while (0)
#define G1_STG_B(CUR, TILE) do {                                      \
    g2l16(b1S0 + (TILE) * 64, B1s + (CUR) * 8192 + 0 * 4096 + ldst);  \
    g2l16(b1S1 + (TILE) * 64, B1s + (CUR) * 8192 + 1 * 4096 + ldst);  \
    g2l16(b3S0 + (TILE) * 64, B3s + (CUR) * 8192 + 0 * 4096 + ldst);  \
    g2l16(b3S1 + (TILE) * 64, B3s + (CUR) * 8192 + 1 * 4096 + ldst);  \
  } while (0)
#define G1_LDALL(CUR, KS2) do {                                                        \
    const int se = ((((KS2) * 4) + kc) ^ sw) * 8;                                      \
    rb1[0] = *(const bf16x8*)(B1s + (CUR) * 8192 + (wn * 32 + lr) * 64 + se);          \
    rb1[1] = *(const bf16x8*)(B1s + (CUR) * 8192 + (wn * 32 + 16 + lr) * 64 + se);     \
    rb3[0] = *(const bf16x8*)(B3s + (CUR) * 8192 + (wn * 32 + lr) * 64 + se);          \
    rb3[1] = *(const bf16x8*)(B3s + (CUR) * 8192 + (wn * 32 + 16 + lr) * 64 + se);     \
    const int ab = (CUR) * 16384 + (wm * 128 + lr) * 64 + se;                          \
    _Pragma("unroll") for (int f = 0; f < 4; ++f) {                                    \
      ra0[f] = *(const bf16x8*)(As + ab + f * 1024);                                   \
      ra1[f] = *(const bf16x8*)(As + ab + 4096 + f * 1024);                            \
    }                                                                                  \
  } while (0)
#define G1_MM2() do {                                                                  \
    _Pragma("unroll") for (int f = 0; f < 4; ++f)                                      \
      _Pragma("unroll") for (int j = 0; j < 2; ++j) {                                  \
        acc1[f][j] = __builtin_amdgcn_mfma_f32_16x16x32_bf16(ra0[f], rb1[j], acc1[f][j], 0, 0, 0); \
        acc3[f][j] = __builtin_amdgcn_mfma_f32_16x16x32_bf16(ra0[f], rb3[j], acc3[f][j], 0, 0, 0); \
      }                                                                                \
    _Pragma("unroll") for (int f = 0; f < 4; ++f)                                      \
      _Pragma("unroll") for (int j = 0; j < 2; ++j) {                                  \
        acc1[4 + f][j] = __builtin_amdgcn_mfma_f32_16x16x32_bf16(ra1[f], rb1[j], acc1[4 + f][j], 0, 0, 0); \
        acc3[4 + f][j] = __builtin_amdgcn_mfma_f32_16x16x32_bf16(ra1[f], rb3[j], acc3[4 + f][j], 0, 0, 0); \
      }                                                                                \
  } while (0)
#define G1_ITER(CUR, KT, DOSTAGE) do {                                                 \
    G1_LDALL(CUR, 0);                                                                  \
    PH_PRE; G1_MM2(); PH_POST;                                                         \
    G1_LDALL(CUR, 1);                                                                  \
    FENCE; SBAR; LGKM0; SCHED0; PRIO(1); G1_MM2(); PRIO(0); SCHED0;                    \
    if (DOSTAGE) { G1_STG_A(CUR, (KT) + 2); G1_STG_B(CUR, (KT) + 2); WAITV(8); }       \
    else WAITV0;                                                                       \
    FENCE; SBAR; SCHED0;                                                               \
  } while (0)

  G1_STG_A(0, 0); G1_STG_B(0, 0);
  G1_STG_A(1, 1); G1_STG_B(1, 1);
  WAITV(8); FENCE; SBAR; SCHED0;

  const int NK = DIM / 64;   // 16
#pragma unroll 1
  for (int kt = 0; kt < NK; kt += 2) {
    G1_ITER(0, kt, (kt + 2) < NK);
    G1_ITER(1, kt + 1, (kt + 3) < NK);
  }

#pragma unroll
  for (int i = 0; i < 8; ++i)
#pragma unroll
    for (int q = 0; q < 4; ++q) {
      int pl = m0 + wm * 128 + i * 16 + kc * 4 + q;
      if (pl >= c) continue;
      unsigned short* hrow = hbuf + (size_t)(base + pl) * HID + n0 + wn * 32 + lr;
#pragma unroll
      for (int j = 0; j < 2; ++j) {
        float v1 = acc1[i][j][q];
        float v3 = acc3[i][j][q];
        float hv = v1 / (1.0f + __expf(-v1)) * v3;   // silu(v1) * v3
        hrow[j * 16] = f2bf(hv);
      }
    }
}

// ============ GEMM2: part[slot][tok] = w * (h @ w2) — BN=256, counted vmcnt ============
// BM=256, BN=256, BK=64, 8 waves (4M x 2N, per-wave 64x128), dbuf LDS 128KB. No atomics.
__global__ __launch_bounds__(512, 1) void gemm2_kernel(const unsigned short* __restrict__ hbuf,
                                                       const unsigned short* __restrict__ w2t,
                                                       const int* __restrict__ cnt,
                                                       const int* __restrict__ idx,
                                                       const float* __restrict__ wslot,
                                                       float* __restrict__ part0,
                                                       float* __restrict__ part1) {
  int e, n0, m0, c, base;
  if (!decode_tile(cnt, NT2, 256, e, n0, m0, c, base)) return;

  __shared__ __align__(16) unsigned short As[2 * 16384];   // [2][256][64]
  __shared__ __align__(16) unsigned short Bs[2 * 16384];   // [2][256][64]

  const int t = threadIdx.x;
  const int wid = t >> 6, lane = t & 63;
  const int wm = wid >> 1, wn = wid & 1;       // 4M x 2N
  const int lr = lane & 15, kc = lane >> 4, sw = lane & 7;
  const int ldst = wid * 512;
  const int trow = t >> 3;
  const int swzk = ((t & 7) ^ ((t >> 3) & 7)) * 8;

  int r0 = imin(base + m0 + trow,       2 * T_TOK - 1);
  int r1 = imin(base + m0 + 64 + trow,  2 * T_TOK - 1);
  int r2 = imin(base + m0 + 128 + trow, 2 * T_TOK - 1);
  int r3 = imin(base + m0 + 192 + trow, 2 * T_TOK - 1);
  const unsigned short* aS0 = hbuf + (size_t)r0 * HID + swzk;
  const unsigned short* aS1 = hbuf + (size_t)r1 * HID + swzk;
  const unsigned short* aS2 = hbuf + (size_t)r2 * HID + swzk;
  const unsigned short* aS3 = hbuf + (size_t)r3 * HID + swzk;
  const unsigned short* w2e = w2t + ((size_t)e * DIM + n0) * HID;
  const unsigned short* bS0 = w2e + (size_t)trow * HID + swzk;
  const unsigned short* bS1 = w2e + (size_t)(64 + trow) * HID + swzk;
  const unsigned short* bS2 = w2e + (size_t)(128 + trow) * HID + swzk;
  const unsigned short* bS3 = w2e + (size_t)(192 + trow) * HID + swzk;

  f32x4 acc[4][8];
#pragma unroll
  for (int i = 0; i < 4; ++i)
#pragma unroll
    for (int j = 0; j < 8; ++j) acc[i][j] = f32x4{0.f, 0.f, 0.f, 0.f};
  bf16x8 ra[4], rb[8];

#define G2_STG(CUR, TILE) do {                                        \
    g2l16(aS0 + (TILE) * 64, As + (CUR) * 16384 + 0 * 4096 + ldst);   \
    g2l16(aS1 + (TILE) * 64, As + (CUR) * 16384 + 1 * 4096 + ldst);   \
    g2l16(aS2 + (TILE) * 64, As + (CUR) * 16384 + 2 * 4096 + ldst);   \
    g2l16(aS3 + (TILE) * 64, As + (CUR) * 16384 + 3 * 4096 + ldst);   \
    g2l16(bS0 + (TILE) * 64, Bs + (CUR) * 16384 + 0 * 4096 + ldst);   \
    g2l16(bS1 + (TILE) * 64, Bs + (CUR) * 16384 + 1 * 4096 + ldst);   \
    g2l16(bS2 + (TILE) * 64, Bs + (CUR) * 16384 + 2 * 4096 + ldst);   \
    g2l16(bS3 + (TILE) * 64, Bs + (CUR) * 16384 + 3 * 4096 + ldst);   \
  } while (0)
#define G2_LD(CUR, KS2) do {                                                          \
    const int se = ((((KS2) * 4) + kc) ^ sw) * 8;                                     \
    const int ab = (CUR) * 16384 + (wm * 64 + lr) * 64 + se;                          \
    _Pragma("unroll") for (int f = 0; f < 4; ++f)                                     \
      ra[f] = *(const bf16x8*)(As + ab + f * 1024);                                   \
    const int bb = (CUR) * 16384 + (wn * 128 + lr) * 64 + se;                         \
    _Pragma("unroll") for (int j = 0; j < 8; ++j)                                     \
      rb[j] = *(const bf16x8*)(Bs + bb + j * 1024);                                   \
  } while (0)
#define G2_MM() do {                                                                  \
    _Pragma("unroll") for (int f = 0; f < 4; ++f)                                     \
      _Pragma("unroll") for (int j = 0; j < 8; ++j)                                   \
        acc[f][j] = __builtin_amdgcn_mfma_f32_16x16x32_bf16(ra[f], rb[j], acc[f][j], 0, 0, 0); \
  } while (0)
#define G2_ITER(CUR, KT, DOSTAGE) do {                                                \
    G2_LD(CUR, 0);                                                                    \
    PH_PRE; G2_MM(); PH_POST;                                                         \
    G2_LD(CUR, 1);                                                                    \
    FENCE; SBAR; LGKM0; SCHED0; PRIO(1); G2_MM(); PRIO(0); SCHED0;                    \
    if (DOSTAGE) { G2_STG(CUR, (KT) + 2); WAITV(8); }                                 \
    else WAITV0;                                                                      \
    FENCE; SBAR; SCHED0;                                                              \
  } while (0)

  G2_STG(0, 0);
  G2_STG(1, 1);
  WAITV(8); FENCE; SBAR; SCHED0;

  const int NK = HID / 64;   // 44
#pragma unroll 1
  for (int kt = 0; kt < NK; kt += 2) {
    G2_ITER(0, kt, (kt + 2) < NK);
    G2_ITER(1, kt + 1, (kt + 3) < NK);
  }

  const int* idx_e = idx + e * T_TOK;
#pragma unroll
  for (int i = 0; i < 4; ++i)
#pragma unroll
    for (int q = 0; q < 4; ++q) {
      int pl = m0 + wm * 64 + i * 16 + kc * 4 + q;
      if (pl >= c) continue;
      int ent = idx_e[pl];
      int tok = ent & 0x1FFF;
      int slot = (ent >> 15) & 1;
      float w = wslot[slot * T_TOK + tok];
      float* pp = slot ? part1 : part0;
      float* orow = pp + (size_t)tok * DIM + n0 + wn * 128 + lr;
#pragma unroll
      for (int j = 0; j < 8; ++j)
        orow[j * 16] = w * acc[i][j][q];
    }
}

// ---------------- combine: out = part0 + part1 ----------------
__global__ __launch_bounds__(256) void combine_kernel(const float* __restrict__ p0,
                                                      const float* __restrict__ p1,
                                                      float* __restrict__ out) {
  int i = blockIdx.x * 256 + threadIdx.x;     // float4 index
  float4 a = ((const float4*)p0)[i];
  float4 b = ((const float4*)p1)[i];
  float4 o;
  o.x = a.x + b.x;
  o.y = a.y + b.y;
  o.z = a.z + b.z;
  o.w = a.w + b.w;
  ((float4*)out)[i] = o;
}

extern "C" void kernel_launch(void* const* d_in, const int* in_sizes, int n_in,
                              void* d_out, int out_size, void* d_ws, size_t ws_size,
                              hipStream_t stream) {
  const float* x  = (const float*)d_in[0];
  const float* gw = (const float*)d_in[1];
  const float* w1 = (const float*)d_in[2];
  const float* w2 = (const float*)d_in[3];
  const float* w3 = (const float*)d_in[4];
  float* out = (float*)d_out;

  // Workspace layout (~249 MB); part[2] aliases w1t/w3t (dead after gemm1).
  char* ws = (char*)d_ws;
  size_t off = 0;
  auto alloc = [&](size_t bytes) {
    char* p = ws + off;
    off += (bytes + 255) & ~(size_t)255;
    return p;
  };
  unsigned short* xb  = (unsigned short*)alloc((size_t)T_TOK * DIM * 2);       // 16.8 MB
  unsigned short* w1t = (unsigned short*)alloc((size_t)NE * DIM * HID * 2);    // 46.1 MB  [E][H][D]
  unsigned short* w3t = (unsigned short*)alloc((size_t)NE * DIM * HID * 2);    // 46.1 MB  [E][H][D]
  unsigned short* w2t = (unsigned short*)alloc((size_t)NE * DIM * HID * 2);    // 46.1 MB  [E][D][H]
  unsigned short* hb  = (unsigned short*)alloc((size_t)2 * T_TOK * HID * 2);   // 92.3 MB
  int*   cnt   = (int*)alloc(NE * sizeof(int));
  int*   idx   = (int*)alloc((size_t)NE * T_TOK * sizeof(int));
  float* wslot = (float*)alloc((size_t)2 * T_TOK * sizeof(float));
  // part aliases w1t..w3t region: 2*T*D*4 = 67.1 MB <= 92.2 MB
  float* part0 = (float*)w1t;
  float* part1 = part0 + (size_t)T_TOK * DIM;

  hipMemsetAsync(cnt, 0, NE * sizeof(int), stream);

  front_kernel<<<RTB + TBLK, 256, 0, stream>>>(x, gw, w1, w3, w2, xb,
                                               w1t, w3t, w2t, cnt, idx, wslot);
  gemm1_kernel<<<72 * NT1, 512, 0, stream>>>(xb, w1t, w3t, cnt, idx, hb);
  gemm2_kernel<<<72 * NT2, 512, 0, stream>>>(hb, w2t, cnt, idx, wslot, part0, part1);
  combine_kernel<<<(T_TOK * DIM) / (4 * 256), 256, 0, stream>>>(part0, part1, out);
}

// Round 14
// 528.869 us; speedup vs baseline: 1.3170x; 1.3170x over previous
//
#include <hip/hip_runtime.h>
#include <math.h>

// Problem constants
#define T_TOK 8192   // B*S tokens
#define DIM   1024   // D
#define HID   2816   // H
#define NE    8      // experts
// K (top-k) = 2

typedef __attribute__((ext_vector_type(4))) float  f32x4;
typedef __attribute__((ext_vector_type(8))) __bf16 bf16x8;
typedef __attribute__((ext_vector_type(8))) unsigned short u16x8;

__device__ __forceinline__ unsigned short f2bf(float f) {
  unsigned int u = __builtin_bit_cast(unsigned int, f);
  unsigned int r = (u + 0x7FFFu + ((u >> 16) & 1u)) >> 16;   // RTNE
  return (unsigned short)r;
}
__device__ __forceinline__ int imin(int a, int b) { return a < b ? a : b; }

// global -> LDS direct DMA, 16B per lane. LDS dest = wave-uniform base + lane*16.
typedef const __attribute__((address_space(1))) void gvoid_t;
typedef __attribute__((address_space(3))) void svoid_t;
__device__ __forceinline__ void g2l16(const void* g, void* l) {
  __builtin_amdgcn_global_load_lds((gvoid_t*)g, (svoid_t*)l, 16, 0, 0);
}

// Pipeline fences (T3/T4): raw s_barrier + counted waits; sched_barrier pins motion.
#define WAITV(N) asm volatile("s_waitcnt vmcnt(" #N ")" ::: "memory")
#define WAITV0 asm volatile("s_waitcnt vmcnt(0)" ::: "memory")
#define LGKM0  asm volatile("s_waitcnt lgkmcnt(0)" ::: "memory")
#define FENCE  asm volatile("" ::: "memory")
#define SBAR   __builtin_amdgcn_s_barrier()
#define SCHED0 __builtin_amdgcn_sched_barrier(0)
#define PRIO(x) __builtin_amdgcn_s_setprio(x)
#define PH_PRE  do { FENCE; SBAR; LGKM0; SCHED0; PRIO(1); } while (0)
#define PH_POST do { PRIO(0); FENCE; SBAR; SCHED0; } while (0)

#define NT1 (HID / 128)   // 22 (gemm1 BN=128)
#define NT2 (DIM / 256)   // 4  (gemm2 BN=256)
#define TPM ((DIM / 64) * (HID / 64) * NE)   // 5632 64x64 tiles per matrix
#define RTB (T_TOK / 4)   // 2048 router blocks
#define TBLK ((3 * TPM) / 2)                 // 8448 transpose blocks (2 tiles each)
#define LDSTR 65          // LDS tile row stride in floats: 2-way banks both phases

// ===== fused front: router (bid < RTB, NO atomics) + 3x transpose-cast =====
__global__ __launch_bounds__(256) void front_kernel(const float* __restrict__ x,
                                                    const float* __restrict__ gw,
                                                    const float* __restrict__ w1,
                                                    const float* __restrict__ w3,
                                                    const float* __restrict__ w2,
                                                    unsigned short* __restrict__ xb,
                                                    unsigned short* __restrict__ w1t,
                                                    unsigned short* __restrict__ w3t,
                                                    unsigned short* __restrict__ w2t,
                                                    int* __restrict__ choice,
                                                    float* __restrict__ wslot) {
  __shared__ float lds[64 * LDSTR];   // 16.6 KB (router blocks don't touch)
  int bid = blockIdx.x;
  if (bid < RTB) {
    // ---------------- router (fused x->bf16 cast); no atomics ----------------
    int wid = threadIdx.x >> 6;
    int lane = threadIdx.x & 63;
    int t = bid * 4 + wid;
    double acc[NE];
#pragma unroll
    for (int e = 0; e < NE; ++e) acc[e] = 0.0;
    const float* xr = x + (size_t)t * DIM;
    unsigned short* xbr = xb + (size_t)t * DIM;
#pragma unroll 4
    for (int i = 0; i < DIM / 64; ++i) {
      int d = i * 64 + lane;
      float xf = xr[d];
      xbr[d] = f2bf(xf);
      double xv = (double)xf;
#pragma unroll
      for (int e = 0; e < NE; ++e) acc[e] += xv * (double)gw[e * DIM + d];
    }
#pragma unroll
    for (int e = 0; e < NE; ++e) {
#pragma unroll
      for (int off = 32; off >= 1; off >>= 1) acc[e] += __shfl_xor(acc[e], off);
    }
    if (lane == 0) {
      int e0 = 0; double s0 = acc[0];
#pragma unroll
      for (int e = 1; e < NE; ++e) if (acc[e] > s0) { s0 = acc[e]; e0 = e; }
      int e1 = -1; double s1 = -1.0e300;
#pragma unroll
      for (int e = 0; e < NE; ++e) if (e != e0 && acc[e] > s1) { s1 = acc[e]; e1 = e; }
      double w0 = 1.0 / (1.0 + exp(s1 - s0));   // softmax over {s0,s1}
      wslot[t] = (float)w0;
      wslot[T_TOK + t] = (float)(1.0 - w0);
      choice[t] = e0 | (e1 << 4);
    }
    return;
  }

  // -------- transpose-cast: fp32 [E][R][C] -> bf16 [E][C][R], 2 tiles pipelined --------
  int tb = bid - RTB;
  const int tr = threadIdx.x >> 4;            // 0..15
  const int tc4 = (threadIdx.x & 15) * 4;     // 0..60
  const int cw = threadIdx.x >> 3;            // 0..31
  const int r8 = (threadIdx.x & 7) * 8;       // 0..56

  const float* sA; unsigned short* dA; int cA, RA;
  const float* sB; unsigned short* dB; int cB, RB;
#pragma unroll
  for (int tau = 0; tau < 2; ++tau) {
    int g = tb * 2 + tau;
    int seg = g / TPM, rr = g % TPM;
    const float* srcm; unsigned short* dstm; int R, C;
    if (seg == 0)      { srcm = w1; dstm = w1t; R = DIM; C = HID; }
    else if (seg == 1) { srcm = w3; dstm = w3t; R = DIM; C = HID; }
    else               { srcm = w2; dstm = w2t; R = HID; C = DIM; }
    int per_e = (R / 64) * (C / 64);
    int e = rr / per_e, tt = rr % per_e;
    int nx = C / 64;
    int c0 = (tt % nx) * 64, r0 = (tt / nx) * 64;
    const float* s = srcm + (size_t)e * R * C + (size_t)(r0 + tr) * C + c0 + tc4;
    unsigned short* d = dstm + (size_t)e * R * C + (size_t)c0 * R + r0;
    if (tau == 0) { sA = s; dA = d; cA = C; RA = R; }
    else          { sB = s; dB = d; cB = C; RB = R; }
  }

  float4 v0[4], v1[4];
#pragma unroll
  for (int s4 = 0; s4 < 4; ++s4)
    v0[s4] = *(const float4*)(sA + (size_t)(s4 * 16) * cA);
#pragma unroll
  for (int s4 = 0; s4 < 4; ++s4) {
    float* lr = &lds[(tr + s4 * 16) * LDSTR + tc4];
    lr[0] = v0[s4].x; lr[1] = v0[s4].y; lr[2] = v0[s4].z; lr[3] = v0[s4].w;
  }
  __syncthreads();
#pragma unroll
  for (int s4 = 0; s4 < 4; ++s4)
    v1[s4] = *(const float4*)(sB + (size_t)(s4 * 16) * cB);
#pragma unroll
  for (int pass = 0; pass < 2; ++pass) {
    int c = cw + pass * 32;
    u16x8 o;
#pragma unroll
    for (int k = 0; k < 8; ++k) o[k] = f2bf(lds[(r8 + k) * LDSTR + c]);
    *(u16x8*)(dA + (size_t)c * RA + r8) = o;
  }
  __syncthreads();
#pragma unroll
  for (int s4 = 0; s4 < 4; ++s4) {
    float* lr = &lds[(tr + s4 * 16) * LDSTR + tc4];
    lr[0] = v1[s4].x; lr[1] = v1[s4].y; lr[2] = v1[s4].z; lr[3] = v1[s4].w;
  }
  __syncthreads();
#pragma unroll
  for (int pass = 0; pass < 2; ++pass) {
    int c = cw + pass * 32;
    u16x8 o;
#pragma unroll
    for (int k = 0; k < 8; ++k) o[k] = f2bf(lds[(r8 + k) * LDSTR + c]);
    *(u16x8*)(dB + (size_t)c * RB + r8) = o;
  }
}

// ===== compact: per-expert stable stream compaction of choice[] (no contended atomics) =====
// idx entry = tok | (slot<<15); cnt[e] = count. Token-ascending -> deterministic.
__global__ __launch_bounds__(1024) void compact_kernel(const int* __restrict__ choice,
                                                       int* __restrict__ cnt,
                                                       int* __restrict__ idx) {
  int e = blockIdx.x;          // 0..7
  __shared__ int wsum[16], wbase[16], blkbase;
  if (threadIdx.x == 0) blkbase = 0;
  __syncthreads();
  int lane = threadIdx.x & 63, wv = threadIdx.x >> 6;   // 16 waves
  int* out = idx + e * T_TOK;
#pragma unroll 1
  for (int chunk = 0; chunk < T_TOK; chunk += 1024) {
    int t = chunk + threadIdx.x;
    int ch = choice[t];
    int ent = -1;
    if ((ch & 15) == e) ent = t;                          // slot 0
    else if (((ch >> 4) & 15) == e) ent = t | (1 << 15);  // slot 1
    unsigned long long mask = __ballot(ent >= 0);
    int mypos = __popcll(mask & ((1ull << lane) - 1ull));
    if (lane == 0) wsum[wv] = __popcll(mask);
    __syncthreads();
    if (threadIdx.x == 0) {
      int s = blkbase;
#pragma unroll
      for (int i = 0; i < 16; ++i) { wbase[i] = s; s += wsum[i]; }
      blkbase = s;
    }
    __syncthreads();
    if (ent >= 0) out[wbase[wv] + mypos] = ent;
    __syncthreads();
  }
  if (threadIdx.x == 0) cnt[e] = blkbase;
}

// ===== self-decode: bid -> (e, n0, m0, c, base) straight from cnt[] =====
__device__ __forceinline__ bool decode_tile(const int* __restrict__ cnt, int ntiles_n,
                                            int nscale, int& e, int& n0, int& m0,
                                            int& c, int& base) {
  int nt = 0;
#pragma unroll
  for (int i = 0; i < NE; ++i) nt += ((cnt[i] + 255) >> 8) * ntiles_n;
  int q = nt >> 3, rr = nt & 7;
  int xcd = blockIdx.x & 7, pos = blockIdx.x >> 3;
  int cap = xcd < rr ? q + 1 : q;
  if (pos >= cap) return false;
  int lid = (xcd < rr ? xcd * (q + 1) : rr * (q + 1) + (xcd - rr) * q) + pos;
  int t1 = 0, s = 0;
  e = 0; c = 0; base = 0; n0 = 0; m0 = 0;
#pragma unroll
  for (int i = 0; i < NE; ++i) {
    int ci = cnt[i];
    int mi = (ci + 255) >> 8;
    int w = mi * ntiles_n;
    if (lid >= t1 && lid < t1 + w) {
      e = i; c = ci; base = s;
      int rem = lid - t1;
      int n = rem / mi;
      n0 = n * nscale;
      m0 = (rem - n * mi) * 256;
    }
    t1 += w; s += ci;
  }
  return true;
}

// ====== GEMM1: h = silu(Xg @ w1) * (Xg @ w3) — 2 phases/K-tile, counted vmcnt ======
// BM=256, BN=128 (dual-B), BK=64, 8 waves (2M x 4N), dbuf LDS 128KB.
__global__ __launch_bounds__(512, 1) void gemm1_kernel(const unsigned short* __restrict__ xb,
                                                       const unsigned short* __restrict__ w1t,
                                                       const unsigned short* __restrict__ w3t,
                                                       const int* __restrict__ cnt,
                                                       const int* __restrict__ idx,
                                                       unsigned short* __restrict__ hbuf) {
  int e, n0, m0, c, base;
  if (!decode_tile(cnt, NT1, 128, e, n0, m0, c, base)) return;

  __shared__ __align__(16) unsigned short As[2 * 16384];   // [2][256][64]
  __shared__ __align__(16) unsigned short B1s[2 * 8192];   // [2][128][64]
  __shared__ __align__(16) unsigned short B3s[2 * 8192];

  const int t = threadIdx.x;
  const int wid = t >> 6, lane = t & 63;
  const int wm = wid >> 2, wn = wid & 3;
  const int lr = lane & 15, kc = lane >> 4, sw = lane & 7;
  const int ldst = wid * 512;           // wave-uniform elems within an 8KB instr chunk
  const int trow = t >> 3;              // 0..63
  const int swzk = ((t & 7) ^ ((t >> 3) & 7)) * 8;   // pre-swizzled source k-chunk

  const int* idx_e = idx + e * T_TOK;
  int g0 = m0 + trow, g1 = m0 + 64 + trow, g2 = m0 + 128 + trow, g3 = m0 + 192 + trow;
  int tk0 = (g0 < c) ? (idx_e[g0] & 0x1FFF) : 0;
  int tk1 = (g1 < c) ? (idx_e[g1] & 0x1FFF) : 0;
  int tk2 = (g2 < c) ? (idx_e[g2] & 0x1FFF) : 0;
  int tk3 = (g3 < c) ? (idx_e[g3] & 0x1FFF) : 0;
  const unsigned short* aS0 = xb + (size_t)tk0 * DIM + swzk;
  const unsigned short* aS1 = xb + (size_t)tk1 * DIM + swzk;
  const unsigned short* aS2 = xb + (size_t)tk2 * DIM + swzk;
  const unsigned short* aS3 = xb + (size_t)tk3 * DIM + swzk;
  const unsigned short* w1e = w1t + ((size_t)e * HID + n0) * DIM;
  const unsigned short* w3e = w3t + ((size_t)e * HID + n0) * DIM;
  const unsigned short* b1S0 = w1e + (size_t)trow * DIM + swzk;
  const unsigned short* b1S1 = w1e + (size_t)(64 + trow) * DIM + swzk;
  const unsigned short* b3S0 = w3e + (size_t)trow * DIM + swzk;
  const unsigned short* b3S1 = w3e + (size_t)(64 + trow) * DIM + swzk;

  f32x4 acc1[8][2], acc3[8][2];
#pragma unroll
  for (int i = 0; i < 8; ++i)
#pragma unroll
    for (int j = 0; j < 2; ++j) {
      acc1[i][j] = f32x4{0.f, 0.f, 0.f, 0.f};
      acc3[i][j] = f32x4{0.f, 0.f, 0.f, 0.f};
    }
  bf16x8 ra0[4], ra1[4], rb1[2], rb3[2];

#define G1_STG_A(CUR, TILE) do {                                      \
    g2l16(aS0 + (TILE) * 64, As + (CUR) * 16384 + 0 * 4096 + ldst);   \
    g2l16(aS1 + (TILE) * 64, As + (CUR) * 16384 + 1 * 4096 + ldst);   \
    g2l16(aS2 + (TILE) * 64, As + (CUR) * 16384 + 2 * 4096 + ldst);   \
    g2l16(aS3 + (TILE) * 64, As + (CUR) * 16384 + 3 * 4096 + ldst);   \
  } while (0)
#define G1_STG_B(CUR, TILE) do {                                      \
    g2l16(b1S0 + (TILE) * 64, B1s + (CUR) * 8192 + 0 * 4096 + ldst);  \
    g2l16(b1S1 + (TILE) * 64, B1s + (CUR) * 8192 + 1 * 4096 + ldst);  \
    g2l16(b3S0 + (TILE) * 64, B3s + (CUR) * 8192 + 0 * 4096 + ldst);  \
    g2l16(b3S1 + (TILE) * 64, B3s + (CUR) * 8192 + 1 * 4096 + ldst);  \
  } while (0)
#define G1_LDALL(CUR, KS2) do {                                                        \
    const int se = ((((KS2) * 4) + kc) ^ sw) * 8;                                      \
    rb1[0] = *(const bf16x8*)(B1s + (CUR) * 8192 + (wn * 32 + lr) * 64 + se);          \
    rb1[1] = *(const bf16x8*)(B1s + (CUR) * 8192 + (wn * 32 + 16 + lr) * 64 + se);     \
    rb3[0] = *(const bf16x8*)(B3s + (CUR) * 8192 + (wn * 32 + lr) * 64 + se);          \
    rb3[1] = *(const bf16x8*)(B3s + (CUR) * 8192 + (wn * 32 + 16 + lr) * 64 + se);     \
    const int ab = (CUR) * 16384 + (wm * 128 + lr) * 64 + se;                          \
    _Pragma("unroll") for (int f = 0; f < 4; ++f) {                                    \
      ra0[f] = *(const bf16x8*)(As + ab + f * 1024);                                   \
      ra1[f] = *(const bf16x8*)(As + ab + 4096 + f * 1024);                            \
    }                                                                                  \
  } while (0)
#define G1_MM2() do {                                                                  \
    _Pragma("unroll") for (int f = 0; f < 4; ++f)                                      \
      _Pragma("unroll") for (int j = 0; j < 2; ++j) {                                  \
        acc1[f][j] = __builtin_amdgcn_mfma_f32_16x16x32_bf16(ra0[f], rb1[j], acc1[f][j], 0, 0, 0); \
        acc3[f][j] = __builtin_amdgcn_mfma_f32_16x16x32_bf16(ra0[f], rb3[j], acc3[f][j], 0, 0, 0); \
      }                                                                                \
    _Pragma("unroll") for (int f = 0; f < 4; ++f)                                      \
      _Pragma("unroll") for (int j = 0; j < 2; ++j) {                                  \
        acc1[4 + f][j] = __builtin_amdgcn_mfma_f32_16x16x32_bf16(ra1[f], rb1[j], acc1[4 + f][j], 0, 0, 0); \
        acc3[4 + f][j] = __builtin_amdgcn_mfma_f32_16x16x32_bf16(ra1[f], rb3[j], acc3[4 + f][j], 0, 0, 0); \
      }                                                                                \
  } while (0)
#define G1_ITER(CUR, KT, DOSTAGE) do {                                                 \
    G1_LDALL(CUR, 0);                                                                  \
    PH_PRE; G1_MM2(); PH_POST;                                                         \
    G1_LDALL(CUR, 1);                                                                  \
    FENCE; SBAR; LGKM0; SCHED0; PRIO(1); G1_MM2(); PRIO(0); SCHED0;                    \
    if (DOSTAGE) { G1_STG_A(CUR, (KT) + 2); G1_STG_B(CUR, (KT) + 2); WAITV(8); }       \
    else WAITV0;                                                                       \
    FENCE; SBAR; SCHED0;                                                               \
  } while (0)

  G1_STG_A(0, 0); G1_STG_B(0, 0);
  G1_STG_A(1, 1); G1_STG_B(1, 1);
  WAITV(8); FENCE; SBAR; SCHED0;

  const int NK = DIM / 64;   // 16
#pragma unroll 1
  for (int kt = 0; kt < NK; kt += 2) {
    G1_ITER(0, kt, (kt + 2) < NK);
    G1_ITER(1, kt + 1, (kt + 3) < NK);
  }

#pragma unroll
  for (int i = 0; i < 8; ++i)
#pragma unroll
    for (int q = 0; q < 4; ++q) {
      int pl = m0 + wm * 128 + i * 16 + kc * 4 + q;
      if (pl >= c) continue;
      unsigned short* hrow = hbuf + (size_t)(base + pl) * HID + n0 + wn * 32 + lr;
#pragma unroll
      for (int j = 0; j < 2; ++j) {
        float v1 = acc1[i][j][q];
        float v3 = acc3[i][j][q];
        float hv = v1 / (1.0f + __expf(-v1)) * v3;   // silu(v1) * v3
        hrow[j * 16] = f2bf(hv);
      }
    }
}

// ============ GEMM2: part[slot][tok] = w * (h @ w2) — BN=256, counted vmcnt ============
// BM=256, BN=256, BK=64, 8 waves (4M x 2N, per-wave 64x128), dbuf LDS 128KB. No atomics.
__global__ __launch_bounds__(512, 1) void gemm2_kernel(const unsigned short* __restrict__ hbuf,
                                                       const unsigned short* __restrict__ w2t,
                                                       const int* __restrict__ cnt,
                                                       const int* __restrict__ idx,
                                                       const float* __restrict__ wslot,
                                                       float* __restrict__ part0,
                                                       float* __restrict__ part1) {
  int e, n0, m0, c, base;
  if (!decode_tile(cnt, NT2, 256, e, n0, m0, c, base)) return;

  __shared__ __align__(16) unsigned short As[2 * 16384];   // [2][256][64]
  __shared__ __align__(16) unsigned short Bs[2 * 16384];   // [2][256][64]

  const int t = threadIdx.x;
  const int wid = t >> 6, lane = t & 63;
  const int wm = wid >> 1, wn = wid & 1;       // 4M x 2N
  const int lr = lane & 15, kc = lane >> 4, sw = lane & 7;
  const int ldst = wid * 512;
  const int trow = t >> 3;
  const int swzk = ((t & 7) ^ ((t >> 3) & 7)) * 8;

  int r0 = imin(base + m0 + trow,       2 * T_TOK - 1);
  int r1 = imin(base + m0 + 64 + trow,  2 * T_TOK - 1);
  int r2 = imin(base + m0 + 128 + trow, 2 * T_TOK - 1);
  int r3 = imin(base + m0 + 192 + trow, 2 * T_TOK - 1);
  const unsigned short* aS0 = hbuf + (size_t)r0 * HID + swzk;
  const unsigned short* aS1 = hbuf + (size_t)r1 * HID + swzk;
  const unsigned short* aS2 = hbuf + (size_t)r2 * HID + swzk;
  const unsigned short* aS3 = hbuf + (size_t)r3 * HID + swzk;
  const unsigned short* w2e = w2t + ((size_t)e * DIM + n0) * HID;
  const unsigned short* bS0 = w2e + (size_t)trow * HID + swzk;
  const unsigned short* bS1 = w2e + (size_t)(64 + trow) * HID + swzk;
  const unsigned short* bS2 = w2e + (size_t)(128 + trow) * HID + swzk;
  const unsigned short* bS3 = w2e + (size_t)(192 + trow) * HID + swzk;

  f32x4 acc[4][8];
#pragma unroll
  for (int i = 0; i < 4; ++i)
#pragma unroll
    for (int j = 0; j < 8; ++j) acc[i][j] = f32x4{0.f, 0.f, 0.f, 0.f};
  bf16x8 ra[4], rb[8];

#define G2_STG(CUR, TILE) do {                                        \
    g2l16(aS0 + (TILE) * 64, As + (CUR) * 16384 + 0 * 4096 + ldst);   \
    g2l16(aS1 + (TILE) * 64, As + (CUR) * 16384 + 1 * 4096 + ldst);   \
    g2l16(aS2 + (TILE) * 64, As + (CUR) * 16384 + 2 * 4096 + ldst);   \
    g2l16(aS3 + (TILE) * 64, As + (CUR) * 16384 + 3 * 4096 + ldst);   \
    g2l16(bS0 + (TILE) * 64, Bs + (CUR) * 16384 + 0 * 4096 + ldst);   \
    g2l16(bS1 + (TILE) * 64, Bs + (CUR) * 16384 + 1 * 4096 + ldst);   \
    g2l16(bS2 + (TILE) * 64, Bs + (CUR) * 16384 + 2 * 4096 + ldst);   \
    g2l16(bS3 + (TILE) * 64, Bs + (CUR) * 16384 + 3 * 4096 + ldst);   \
  } while (0)
#define G2_LD(CUR, KS2) do {                                                          \
    const int se = ((((KS2) * 4) + kc) ^ sw) * 8;                                     \
    const int ab = (CUR) * 16384 + (wm * 64 + lr) * 64 + se;                          \
    _Pragma("unroll") for (int f = 0; f < 4; ++f)                                     \
      ra[f] = *(const bf16x8*)(As + ab + f * 1024);                                   \
    const int bb = (CUR) * 16384 + (wn * 128 + lr) * 64 + se;                         \
    _Pragma("unroll") for (int j = 0; j < 8; ++j)                                     \
      rb[j] = *(const bf16x8*)(Bs + bb + j * 1024);                                   \
  } while (0)
#define G2_MM() do {                                                                  \
    _Pragma("unroll") for (int f = 0; f < 4; ++f)                                     \
      _Pragma("unroll") for (int j = 0; j < 8; ++j)                                   \
        acc[f][j] = __builtin_amdgcn_mfma_f32_16x16x32_bf16(ra[f], rb[j], acc[f][j], 0, 0, 0); \
  } while (0)
#define G2_ITER(CUR, KT, DOSTAGE) do {                                                \
    G2_LD(CUR, 0);                                                                    \
    PH_PRE; G2_MM(); PH_POST;                                                         \
    G2_LD(CUR, 1);                                                                    \
    FENCE; SBAR; LGKM0; SCHED0; PRIO(1); G2_MM(); PRIO(0); SCHED0;                    \
    if (DOSTAGE) { G2_STG(CUR, (KT) + 2); WAITV(8); }                                 \
    else WAITV0;                                                                      \
    FENCE; SBAR; SCHED0;                                                              \
  } while (0)

  G2_STG(0, 0);
  G2_STG(1, 1);
  WAITV(8); FENCE; SBAR; SCHED0;

  const int NK = HID / 64;   // 44
#pragma unroll 1
  for (int kt = 0; kt < NK; kt += 2) {
    G2_ITER(0, kt, (kt + 2) < NK);
    G2_ITER(1, kt + 1, (kt + 3) < NK);
  }

  const int* idx_e = idx + e * T_TOK;
#pragma unroll
  for (int i = 0; i < 4; ++i)
#pragma unroll
    for (int q = 0; q < 4; ++q) {
      int pl = m0 + wm * 64 + i * 16 + kc * 4 + q;
      if (pl >= c) continue;
      int ent = idx_e[pl];
      int tok = ent & 0x1FFF;
      int slot = (ent >> 15) & 1;
      float w = wslot[slot * T_TOK + tok];
      float* pp = slot ? part1 : part0;
      float* orow = pp + (size_t)tok * DIM + n0 + wn * 128 + lr;
#pragma unroll
      for (int j = 0; j < 8; ++j)
        orow[j * 16] = w * acc[i][j][q];
    }
}

// ---------------- combine: out = part0 + part1 ----------------
__global__ __launch_bounds__(256) void combine_kernel(const float* __restrict__ p0,
                                                      const float* __restrict__ p1,
                                                      float* __restrict__ out) {
  int i = blockIdx.x * 256 + threadIdx.x;     // float4 index
  float4 a = ((const float4*)p0)[i];
  float4 b = ((const float4*)p1)[i];
  float4 o;
  o.x = a.x + b.x;
  o.y = a.y + b.y;
  o.z = a.z + b.z;
  o.w = a.w + b.w;
  ((float4*)out)[i] = o;
}

extern "C" void kernel_launch(void* const* d_in, const int* in_sizes, int n_in,
                              void* d_out, int out_size, void* d_ws, size_t ws_size,
                              hipStream_t stream) {
  const float* x  = (const float*)d_in[0];
  const float* gw = (const float*)d_in[1];
  const float* w1 = (const float*)d_in[2];
  const float* w2 = (const float*)d_in[3];
  const float* w3 = (const float*)d_in[4];
  float* out = (float*)d_out;

  // Workspace layout (~249 MB); part[2] aliases w1t/w3t (dead after gemm1).
  char* ws = (char*)d_ws;
  size_t off = 0;
  auto alloc = [&](size_t bytes) {
    char* p = ws + off;
    off += (bytes + 255) & ~(size_t)255;
    return p;
  };
  unsigned short* xb  = (unsigned short*)alloc((size_t)T_TOK * DIM * 2);       // 16.8 MB
  unsigned short* w1t = (unsigned short*)alloc((size_t)NE * DIM * HID * 2);    // 46.1 MB  [E][H][D]
  unsigned short* w3t = (unsigned short*)alloc((size_t)NE * DIM * HID * 2);    // 46.1 MB  [E][H][D]
  unsigned short* w2t = (unsigned short*)alloc((size_t)NE * DIM * HID * 2);    // 46.1 MB  [E][D][H]
  unsigned short* hb  = (unsigned short*)alloc((size_t)2 * T_TOK * HID * 2);   // 92.3 MB
  int*   cnt    = (int*)alloc(NE * sizeof(int));
  int*   choice = (int*)alloc((size_t)T_TOK * sizeof(int));
  int*   idx    = (int*)alloc((size_t)NE * T_TOK * sizeof(int));
  float* wslot  = (float*)alloc((size_t)2 * T_TOK * sizeof(float));
  // part aliases w1t..w3t region: 2*T*D*4 = 67.1 MB <= 92.2 MB
  float* part0 = (float*)w1t;
  float* part1 = part0 + (size_t)T_TOK * DIM;

  front_kernel<<<RTB + TBLK, 256, 0, stream>>>(x, gw, w1, w3, w2, xb,
                                               w1t, w3t, w2t, choice, wslot);
  compact_kernel<<<NE, 1024, 0, stream>>>(choice, cnt, idx);
  gemm1_kernel<<<72 * NT1, 512, 0, stream>>>(xb, w1t, w3t, cnt, idx, hb);
  gemm2_kernel<<<72 * NT2, 512, 0, stream>>>(hb, w2t, cnt, idx, wslot, part0, part1);
  combine_kernel<<<(T_TOK * DIM) / (4 * 256), 256, 0, stream>>>(part0, part1, out);
}